// Round 25
// baseline (257.287 us; speedup 1.0000x reference)
//
#include <hip/hip_runtime.h>
#include <hip/hip_bf16.h>

#define NE 8
#define HD 256
#define NT 64
#define NTHREADS 256
#define WPITCH 32
#define SLICE_ELEMS (HD * WPITCH)      // 8192 elems = 16384 B per K=32 slice

typedef __attribute__((ext_vector_type(8))) short short8;
typedef __attribute__((ext_vector_type(4))) float f32x4;
typedef __attribute__((ext_vector_type(16))) float f32x16;

__device__ __forceinline__ unsigned short f2bf_u16(float f) {
    union { __hip_bfloat16 b; unsigned short u; } v;
    v.b = __float2bfloat16(f);          // HW RNE convert
    return v.u;
}
__device__ __forceinline__ unsigned int pack2bf(float lo, float hi) {
    return (unsigned int)f2bf_u16(lo) | ((unsigned int)f2bf_u16(hi) << 16);
}
// hi/lo bf16 split: v ≈ hi + lo with |v - hi - lo| <= 2^-16 |v|.
__device__ __forceinline__ void bfsplit(float v, unsigned short& hi, unsigned short& lo) {
    hi = f2bf_u16(v);
    union { unsigned int u; float f; } c; c.u = ((unsigned int)hi) << 16;
    lo = f2bf_u16(v - c.f);
}
// Act LDS swizzle (element units), proven in R12/R17.
__device__ __forceinline__ int swz(int row, int col) {
    return row * HD + (col ^ ((row & 7) << 3));
}

// Weights pre-swizzled: Wp[e][slice s][n][32], [n][kk] = W[k=s*32+kk][n].
__global__ void prep_weights(const float* __restrict__ W1, const float* __restrict__ W2,
                             unsigned short* __restrict__ W1p, unsigned short* __restrict__ W2p) {
    int idx = blockIdx.x * blockDim.x + threadIdx.x;
    const int TOT = NE * 8 * SLICE_ELEMS;
    if (idx >= TOT) return;
    int kk = idx & 31;
    int n  = (idx >> 5) & 255;
    int s  = (idx >> 13) & 7;
    int e  = idx >> 16;
    int k = s * 32 + kk;
    W1p[idx] = f2bf_u16(W1[(e * HD + k) * HD + n]);
    W2p[idx] = f2bf_u16(W2[(e * HD + k) * HD + n]);
}

// Layer-0 as one K=16 MFMA step (slots 0..10; bias folded; pairs with cbufK).
__global__ void prep_w0(const float* __restrict__ W0, const float* __restrict__ b0,
                        unsigned short* __restrict__ W0k) {
    int idx = blockIdx.x * blockDim.x + threadIdx.x;   // e*HD + n
    if (idx >= NE * HD) return;
    int n = idx & 255, e = idx >> 8;
    float wx = W0[(e*3+0)*HD + n], wy = W0[(e*3+1)*HD + n], wz = W0[(e*3+2)*HD + n];
    float bb = b0[e*HD + n];
    unsigned short xh,xl,yh,yl,zh,zl,bh,bl;
    bfsplit(wx,xh,xl); bfsplit(wy,yh,yl); bfsplit(wz,zh,zl); bfsplit(bb,bh,bl);
    unsigned short s[32] = {xh,xh,xl, yh,yh,yl, zh,zh,zl, bh,bl};  // rest zero
    unsigned short* dst = W0k + idx * 32;
    #pragma unroll
    for (int i = 0; i < 32; ++i) dst[i] = s[i];
}

// One K=16 step, 32x32x16 MFMA: 2 af (L2, own neuron quarter) x 2 bf (Act LDS)
// -> 4 MFMAs. A/B frags: row/col = lane&31, k = step*16 + (lane>>5)*8 + 0..7.
#define KSTEP32(WSRC, S16)                                                                    \
    {                                                                                         \
        const unsigned short* Ar = (WSRC) + ((S16) >> 1) * SLICE_ELEMS                        \
                                 + (g*64 + l31) * WPITCH + ((S16) & 1) * 16 + kh8;            \
        short8 af0 = *(const short8*)(Ar);                                                    \
        short8 af1 = *(const short8*)(Ar + 32 * WPITCH);                                      \
        short8 bf0 = *(const short8*)(Act + swz(l31,      (S16)*16 + kh8));                   \
        short8 bf1 = *(const short8*)(Act + swz(32 + l31, (S16)*16 + kh8));                   \
        acc[0][0] = __builtin_amdgcn_mfma_f32_32x32x16_bf16(af0, bf0, acc[0][0], 0,0,0);      \
        acc[0][1] = __builtin_amdgcn_mfma_f32_32x32x16_bf16(af0, bf1, acc[0][1], 0,0,0);      \
        acc[1][0] = __builtin_amdgcn_mfma_f32_32x32x16_bf16(af1, bf0, acc[1][0], 0,0,0);      \
        acc[1][1] = __builtin_amdgcn_mfma_f32_32x32x16_bf16(af1, bf1, acc[1][1], 0,0,0);      \
    }

#define ACC_CLEAR()                                           \
    _Pragma("unroll")                                         \
    for (int mt = 0; mt < 2; ++mt)                            \
        _Pragma("unroll")                                     \
        for (int pt = 0; pt < 2; ++pt)                        \
            _Pragma("unroll")                                 \
            for (int i = 0; i < 16; ++i)                      \
                acc[mt][pt][i] = 0.f;

// One expert per block: blockIdx = tile*8 + e (XCD round-robin -> all blocks
// on an XCD share the expert; weights L2-resident). 4 waves, wave g owns
// neurons [g*64,+64) x ALL 64 points. 36 KB LDS; 5 barriers; K-loops barrier-
// free (weights direct from L2). (256,3): no spill (R23's (,4) pinned 64 VGPR).
__global__ __launch_bounds__(NTHREADS, 3) void moe_expert(
    const float* __restrict__ coords, int npts,
    const unsigned short* __restrict__ W0k, const float* __restrict__ b1,
    const unsigned short* __restrict__ W1p,
    const unsigned short* __restrict__ W2p, const float* __restrict__ b2,
    const float* __restrict__ W3, const float* __restrict__ b3,
    float* __restrict__ ws)
{
    __shared__ __align__(16) unsigned short Act[NT * HD];      // 32 KB
    __shared__ __align__(16) unsigned char aux[NT * 32 * 2];   // 4 KB: cbufK / pscr
    unsigned short* cbufK = (unsigned short*)aux;   // phases 0-1 only
    float* pscr = (float*)aux;                      // tail only (disjoint in time)

    const int t = threadIdx.x;
    const int lane = t & 63;
    const int g = t >> 6;        // 0..3: neuron group of 64
    const int l31 = lane & 31;   // row (A) / point-col (B) within 32x32 tile
    const int kh8 = (lane >> 5) * 8;   // k-half offset
    const int kh4 = (lane >> 5) * 4;   // C/D row sub-offset
    const int e = blockIdx.x & 7;
    const int p0 = (blockIdx.x >> 3) * NT;

    const unsigned short* W0e = W0k + e * SLICE_ELEMS;
    const unsigned short* W1e = W1p + e * 8 * SLICE_ELEMS;
    const unsigned short* W2e = W2p + e * 8 * SLICE_ELEMS;

    // ---- phase 0: build per-point L0 B-slots (hi/lo split) ----
    if (t < NT) {
        int p = p0 + t;
        int pc = p < npts ? p : npts - 1;      // clamp; store masked later
        float x = coords[pc*3], y = coords[pc*3+1], z = coords[pc*3+2];
        unsigned short xh,xl,yh,yl,zh,zl;
        bfsplit(x,xh,xl); bfsplit(y,yh,yl); bfsplit(z,zh,zl);
        const unsigned short ONE = 0x3F80;     // bf16(1.0)
        union { unsigned short s[32]; uint4 q[4]; } pk;
        #pragma unroll
        for (int i = 0; i < 32; ++i) pk.s[i] = 0;
        pk.s[0]=xh; pk.s[1]=xl; pk.s[2]=xh;
        pk.s[3]=yh; pk.s[4]=yl; pk.s[5]=yh;
        pk.s[6]=zh; pk.s[7]=zl; pk.s[8]=zh;
        pk.s[9]=ONE; pk.s[10]=ONE;
        uint4* dst = (uint4*)(cbufK + t * 32);
        dst[0]=pk.q[0]; dst[1]=pk.q[1]; dst[2]=pk.q[2]; dst[3]=pk.q[3];
    }
    __syncthreads();                    // [1] cbufK visible

    f32x16 acc[2][2];
    ACC_CLEAR()

    // ---- phase 1: L0 as one 32x32x16 step (af from L2, bias in slots) ----
    {
        const unsigned short* Ar = W0e + (g*64 + l31) * WPITCH + kh8;
        short8 af0 = *(const short8*)(Ar);
        short8 af1 = *(const short8*)(Ar + 32 * WPITCH);
        short8 bf0 = *(const short8*)(cbufK + l31 * 32 + kh8);
        short8 bf1 = *(const short8*)(cbufK + (32 + l31) * 32 + kh8);
        acc[0][0] = __builtin_amdgcn_mfma_f32_32x32x16_bf16(af0, bf0, acc[0][0], 0,0,0);
        acc[0][1] = __builtin_amdgcn_mfma_f32_32x32x16_bf16(af0, bf1, acc[0][1], 0,0,0);
        acc[1][0] = __builtin_amdgcn_mfma_f32_32x32x16_bf16(af1, bf0, acc[1][0], 0,0,0);
        acc[1][1] = __builtin_amdgcn_mfma_f32_32x32x16_bf16(af1, bf1, acc[1][1], 0,0,0);
        // L0 epilogue: relu + pack -> Act. C/D: col(point)=l31,
        // row(neuron)=(r&3)+8*(r>>2)+4*(lane>>5) — m74/m101-verified.
        #pragma unroll
        for (int mt = 0; mt < 2; ++mt)
            #pragma unroll
            for (int pt = 0; pt < 2; ++pt) {
                const int p = pt*32 + l31;
                #pragma unroll
                for (int q = 0; q < 4; ++q) {
                    const int nb = g*64 + mt*32 + q*8 + kh4;
                    unsigned int lo = pack2bf(fmaxf(acc[mt][pt][4*q+0], 0.f),
                                              fmaxf(acc[mt][pt][4*q+1], 0.f));
                    unsigned int hi = pack2bf(fmaxf(acc[mt][pt][4*q+2], 0.f),
                                              fmaxf(acc[mt][pt][4*q+3], 0.f));
                    *(uint2*)(Act + swz(p, nb)) = make_uint2(lo, hi);
                }
            }
    }
    __syncthreads();                    // [2] Act W->R boundary

    ACC_CLEAR()
    // ---- layer 1: 16 K=16 steps, barrier-free (af streamed from L2) ----
    #pragma unroll
    for (int s16 = 0; s16 < 16; ++s16) {
        KSTEP32(W1e, s16)
    }
    __syncthreads();                    // [3] all Act reads done (R->W boundary)

    // ---- layer-1 epilogue: bias+relu -> Act in place ----
    #pragma unroll
    for (int mt = 0; mt < 2; ++mt)
        #pragma unroll
        for (int q = 0; q < 4; ++q) {
            const int nb = g*64 + mt*32 + q*8 + kh4;
            const f32x4 bb = *(const f32x4*)(b1 + e*HD + nb);
            #pragma unroll
            for (int pt = 0; pt < 2; ++pt) {
                const int p = pt*32 + l31;
                unsigned int lo = pack2bf(fmaxf(acc[mt][pt][4*q+0] + bb[0], 0.f),
                                          fmaxf(acc[mt][pt][4*q+1] + bb[1], 0.f));
                unsigned int hi = pack2bf(fmaxf(acc[mt][pt][4*q+2] + bb[2], 0.f),
                                          fmaxf(acc[mt][pt][4*q+3] + bb[3], 0.f));
                *(uint2*)(Act + swz(p, nb)) = make_uint2(lo, hi);
            }
        }
    __syncthreads();                    // [4] Act W->R boundary

    ACC_CLEAR()
    // ---- layer 2: 16 K=16 steps, barrier-free ----
    #pragma unroll
    for (int s16 = 0; s16 < 16; ++s16) {
        KSTEP32(W2e, s16)
    }

    // ---- fused layer-2 epilogue + layer 3 (fp32, in registers) ----
    {
        float sum[2] = {0.f, 0.f};
        #pragma unroll
        for (int mt = 0; mt < 2; ++mt)
            #pragma unroll
            for (int q = 0; q < 4; ++q) {
                const int nb = g*64 + mt*32 + q*8 + kh4;
                const f32x4 bb = *(const f32x4*)(b2 + e*HD + nb);
                const f32x4 w3 = *(const f32x4*)(W3 + e*HD + nb);
                #pragma unroll
                for (int pt = 0; pt < 2; ++pt)
                    #pragma unroll
                    for (int r = 0; r < 4; ++r)
                        sum[pt] += fmaxf(acc[mt][pt][4*q+r] + bb[r], 0.f) * w3[r];
            }
        #pragma unroll
        for (int pt = 0; pt < 2; ++pt) {
            float s = sum[pt] + __shfl_xor(sum[pt], 32);   // reduce k-halves
            if (lane < 32) pscr[(pt*32 + l31) * 4 + g] = s;  // pscr aliases cbufK
        }                                                    // (last read: phase 1)
    }
    __syncthreads();                    // [5] pscr W->R boundary
    if (t < NT) {
        f32x4 v = *(const f32x4*)(pscr + t * 4);
        int p = p0 + t;
        if (p < npts) ws[e * npts + p] = v[0] + v[1] + v[2] + v[3] + b3[e];
    }
}

// Max over the 8 experts' partials.
__global__ void moe_reduce(const float* __restrict__ ws, float* __restrict__ out, int npts) {
    int p = blockIdx.x * 256 + threadIdx.x;
    if (p >= npts) return;
    float m = ws[p];
    #pragma unroll
    for (int e = 1; e < NE; ++e) m = fmaxf(m, ws[e * npts + p]);
    out[p] = m;
}

extern "C" void kernel_launch(void* const* d_in, const int* in_sizes, int n_in,
                              void* d_out, int out_size, void* d_ws, size_t ws_size,
                              hipStream_t stream) {
    const float* coords = (const float*)d_in[0];
    const float* W0 = (const float*)d_in[1];
    const float* b0 = (const float*)d_in[2];
    const float* W1 = (const float*)d_in[3];
    const float* b1 = (const float*)d_in[4];
    const float* W2 = (const float*)d_in[5];
    const float* b2 = (const float*)d_in[6];
    const float* W3 = (const float*)d_in[7];
    const float* b3 = (const float*)d_in[8];
    const int npts = in_sizes[0] / 3;

    unsigned short* W1p = (unsigned short*)d_ws;                   // 1 MB
    unsigned short* W2p = W1p + NE * 8 * SLICE_ELEMS;              // 1 MB
    unsigned short* W0k = W2p + NE * 8 * SLICE_ELEMS;              // 128 KB
    float* eout = (float*)(W0k + NE * SLICE_ELEMS);                // 3.2 MB

    const int PREP_TOT = NE * 8 * SLICE_ELEMS;
    prep_weights<<<(PREP_TOT + 255) / 256, 256, 0, stream>>>(W1, W2, W1p, W2p);
    prep_w0<<<(NE * HD + 255) / 256, 256, 0, stream>>>(W0, b0, W0k);

    int ntiles = (npts + NT - 1) / NT;
    moe_expert<<<ntiles * NE, NTHREADS, 0, stream>>>(
        coords, npts, W0k, b1, W1p, W2p, b2, W3, b3, eout);

    moe_reduce<<<(npts + 255) / 256, 256, 0, stream>>>(eout, (float*)d_out, npts);
}